// Round 3
// baseline (17314.861 us; speedup 1.0000x reference)
//
#include <hip/hip_runtime.h>
#include <math.h>

#define TT 2048
#define NKEYS 50000
#define EE 128
#define HH 512
#define H3 1536
#define DH 256
#define VOCAB 1704
#define NLOC 100

#define GB 32      // GRU blocks
#define GC 16      // h-elements per GRU block

#define QT 32      // flash queries per block
#define KT 64      // flash key tile
#define NSPL 4     // flash N-splits
#define SLICE 12500
#define KSTR 260   // padded LDS stride (f32) for K tile

// ---- workspace layout (float offsets) ----
static constexpr size_t OFF_Y     = 0;
static constexpr size_t OFF_GX    = OFF_Y    + (size_t)TT*EE;
static constexpr size_t OFF_OUT   = OFF_GX   + (size_t)TT*H3;
static constexpr size_t OFF_HBUF  = OFF_OUT  + (size_t)TT*HH;        // 2*HH uint64 = 4*HH floats
static constexpr size_t OFF_MG    = OFF_HBUF + 4*HH;
static constexpr size_t OFF_ML    = OFF_MG   + (size_t)TT*DH;
static constexpr size_t OFF_C     = OFF_ML   + (size_t)TT*DH;
static constexpr size_t OFF_CG    = OFF_C    + (size_t)TT*DH;
static constexpr size_t OFF_BETA  = OFF_CG   + (size_t)TT*DH;
static constexpr size_t OFF_PGEN  = OFF_BETA + (size_t)TT*NLOC;
static constexpr size_t OFF_OP    = OFF_PGEN + TT;
static constexpr size_t OFF_MP    = OFF_OP   + (size_t)NSPL*TT*DH;
static constexpr size_t OFF_LP    = OFF_MP   + (size_t)NSPL*TT;

// ---------------- embedding + gx = y@W_ih^T + b_ih ----------------
__global__ void k_embed_gx(const int* __restrict__ X, const float* __restrict__ emb,
                           const float* __restrict__ W_ih, const float* __restrict__ b_ih,
                           float* __restrict__ Y, float* __restrict__ GX){
  int t = blockIdx.x, tid = threadIdx.x;
  __shared__ float yr[EE];
  int xid = X[t];
  if (tid < EE){ float v = emb[(size_t)xid*EE + tid]; yr[tid] = v; Y[(size_t)t*EE + tid] = v; }
  __syncthreads();
  for (int i=0;i<6;i++){
    int r = tid + 256*i;
    const float4* w = (const float4*)(W_ih + (size_t)r*EE);
    float acc = b_ih[r];
    #pragma unroll
    for (int k4=0;k4<EE/4;k4++){
      float4 wv = w[k4];
      acc += wv.x*yr[k4*4] + wv.y*yr[k4*4+1] + wv.z*yr[k4*4+2] + wv.w*yr[k4*4+3];
    }
    GX[(size_t)t*H3 + r] = acc;
  }
}

// ---------------- GRU scan: poll-into-registers, single barrier per step ----------------
// Thread (wave,lane) polls exactly the 8 packed (seq|h) words it needs for its
// matvec columns {lane+64m}. Writer lanes (tid<16) carry their own h element in
// a register across steps. One __syncthreads per step (gh ready). Slot reuse by
// step parity is race-free: a wave can only overwrite gh / a writer can only
// store seq t+1 after polls that transitively require all waves done with seq t-1.
__global__ __launch_bounds__(256) void k_gru(const float* __restrict__ GX, const float* __restrict__ W_hh,
          const float* __restrict__ b_hh, const float* __restrict__ glo, const float* __restrict__ loch,
          float* __restrict__ out, unsigned long long* hbuf){
  __shared__ float wl[48*512];
  __shared__ float gh[48];
  int b = blockIdx.x, tid = threadIdx.x;
  int i0 = b*GC;
  for (int idx = tid; idx < 48*128; idx += 256){
    int r = idx >> 7, c4 = idx & 127;
    int grow = (r<16) ? (i0 + r) : (r<32) ? (512 + i0 + (r-16)) : (1024 + i0 + (r-32));
    ((float4*)wl)[idx] = ((const float4*)W_hh)[(size_t)grow*128 + c4];
  }
  int wave = tid>>6, lane = tid&63;
  float hreg[8];
  #pragma unroll
  for (int m=0;m<8;m++){
    int c = lane + 64*m;
    hreg[m] = (c < 256) ? glo[c] : loch[c-256];
  }
  float bhr=0.f,bhz=0.f,bhn=0.f, hprev=0.f;
  if (tid < GC){
    bhr = b_hh[i0+tid]; bhz = b_hh[512+i0+tid]; bhn = b_hh[1024+i0+tid];
    hprev = (i0+tid < 256) ? glo[i0+tid] : loch[i0+tid-256];
  }
  __syncthreads();
  for (int t=0;t<TT;t++){
    // issue gx loads early (consumed after barrier; latency hides under matvec)
    float gxr=0.f,gxz=0.f,gxn=0.f;
    if (tid < GC){
      size_t gbse = (size_t)t*H3;
      gxr = GX[gbse + i0+tid]; gxz = GX[gbse + 512+i0+tid]; gxn = GX[gbse + 1024+i0+tid];
    }
    #pragma unroll
    for (int rr=0; rr<12; rr++){
      int row = wave*12 + rr;
      const float* wr = &wl[row*512];
      float s = 0.f;
      #pragma unroll
      for (int m=0;m<8;m++) s = fmaf(wr[lane+64*m], hreg[m], s);
      #pragma unroll
      for (int off=32; off>0; off>>=1) s += __shfl_xor(s, off, 64);
      if (lane==0) gh[row] = s;
    }
    __syncthreads();   // gh ready; also guarantees all waves consumed hreg of step t
    if (tid < GC){
      float rg = 1.f/(1.f + __expf(-(gxr + gh[tid]    + bhr)));
      float zg = 1.f/(1.f + __expf(-(gxz + gh[16+tid] + bhz)));
      float nx = gxn + bhn + rg*gh[32+tid];
      float ex = __expf(-2.f*fabsf(nx));
      float tt2 = (1.f-ex)/(1.f+ex);
      float ng = (nx >= 0.f) ? tt2 : -tt2;
      float hn = (1.f - zg)*ng + zg*hprev;
      out[(size_t)t*HH + i0 + tid] = hn;
      unsigned long long pk = ((unsigned long long)(unsigned)(t+1) << 32) | (unsigned long long)__float_as_uint(hn);
      __hip_atomic_store(&hbuf[((t+1)&1)*HH + i0 + tid], pk, __ATOMIC_RELAXED, __HIP_MEMORY_SCOPE_AGENT);
      hprev = hn;
    }
    if (t+1 < TT){
      unsigned want = (unsigned)(t+1);
      const unsigned long long* hb = &hbuf[((t+1)&1)*HH];
      unsigned long long v[8];
      unsigned rdym = 0;
      do {
        #pragma unroll
        for (int m=0;m<8;m++){
          if (!(rdym & (1u<<m))){
            unsigned long long x = __hip_atomic_load(&hb[lane + 64*m], __ATOMIC_RELAXED, __HIP_MEMORY_SCOPE_AGENT);
            if ((unsigned)(x>>32) == want){ v[m] = x; rdym |= (1u<<m); }
          }
        }
      } while (rdym != 0xFFu);
      #pragma unroll
      for (int m=0;m<8;m++) hreg[m] = __uint_as_float((unsigned)v[m]);
    }
  }
}

// ---------------- M_g = out@W_ga_g, M_l = out@W_ga_l, pgen base ----------------
__global__ void k_proj(const float* __restrict__ out, const float* __restrict__ Y,
                       const float* __restrict__ Wg, const float* __restrict__ Wl,
                       const float* __restrict__ wh, const float* __restrict__ wy,
                       float* __restrict__ MG, float* __restrict__ ML, float* __restrict__ PGB){
  int t = blockIdx.x, tid = threadIdx.x;
  __shared__ float orow[512];
  __shared__ float red[256];
  orow[tid]     = out[(size_t)t*HH + tid];
  orow[tid+256] = out[(size_t)t*HH + tid+256];
  __syncthreads();
  float mg=0.f, ml=0.f;
  for (int h=0; h<HH; h++){
    float ov = orow[h];
    mg = fmaf(ov, Wg[(size_t)h*DH + tid], mg);
    ml = fmaf(ov, Wl[(size_t)h*DH + tid], ml);
  }
  MG[(size_t)t*DH + tid] = mg;
  ML[(size_t)t*DH + tid] = ml;
  float pr = orow[tid]*wh[tid] + orow[tid+256]*wh[tid+256];
  if (tid < EE) pr += Y[(size_t)t*EE + tid]*wy[tid];
  red[tid] = pr;
  __syncthreads();
  for (int s=128; s>0; s>>=1){ if (tid < s) red[tid] += red[tid+s]; __syncthreads(); }
  if (tid==0) PGB[t] = red[0];
}

// ---------------- local attention + p_gen ----------------
__global__ void k_local(const float* __restrict__ ML, const float* __restrict__ locout,
                        const float* __restrict__ wc, const float* __restrict__ PGB,
                        float* __restrict__ C, float* __restrict__ BETA, float* __restrict__ PGEN){
  int t = blockIdx.x, tid = threadIdx.x; // 128 threads
  __shared__ float mlr[DH];
  __shared__ float sl[NLOC];
  __shared__ float crow[DH];
  __shared__ float red[128];
  __shared__ float mx; __shared__ float inv;
  mlr[tid]     = ML[(size_t)t*DH + tid];
  mlr[tid+128] = ML[(size_t)t*DH + tid+128];
  __syncthreads();
  if (tid < NLOC){
    const float* gl = locout + (size_t)tid*8*DH;
    float s=0.f;
    for (int e=0;e<DH;e++) s = fmaf(gl[e], mlr[e], s);
    sl[tid] = s;
  }
  __syncthreads();
  if (tid==0){ float m = sl[0]; for (int j=1;j<NLOC;j++) m = fmaxf(m, sl[j]); mx = m; }
  __syncthreads();
  if (tid < NLOC) sl[tid] = __expf(sl[tid]-mx);
  __syncthreads();
  if (tid==0){ float su=0.f; for (int j=0;j<NLOC;j++) su += sl[j]; inv = 1.f/su; }
  __syncthreads();
  if (tid < NLOC){ sl[tid] *= inv; BETA[(size_t)t*NLOC + tid] = sl[tid]; }
  __syncthreads();
  {
    float c0=0.f, c1=0.f;
    for (int j=0;j<NLOC;j++){
      float ga = sl[j];
      c0 = fmaf(ga, locout[(size_t)j*8*DH + tid],     c0);
      c1 = fmaf(ga, locout[(size_t)j*8*DH + tid+128], c1);
    }
    C[(size_t)t*DH + tid]     = c0;
    C[(size_t)t*DH + tid+128] = c1;
    crow[tid] = c0; crow[tid+128] = c1;
  }
  __syncthreads();
  red[tid] = crow[tid]*wc[tid] + crow[tid+128]*wc[tid+128];
  __syncthreads();
  for (int s=64;s>0;s>>=1){ if (tid<s) red[tid]+=red[tid+s]; __syncthreads(); }
  if (tid==0){
    float x = PGB[t] + red[0];
    PGEN[t] = (x > 0.f) ? x : 0.2f*x;
  }
}

// ---------------- global flash attention (f32), 4-way N split ----------------
__global__ __launch_bounds__(256) void k_flash(const float* __restrict__ MG, const float* __restrict__ G,
        float* __restrict__ OP, float* __restrict__ MP, float* __restrict__ LP){
  __shared__ float Mt[QT*DH];
  __shared__ float Kt[KT*KSTR];
  __shared__ float Pt[QT*(KT+2)];
  __shared__ float m_st[QT]; __shared__ float l_st[QT]; __shared__ float al_sh[QT];
  int bid = blockIdx.x;
  int qb = bid & 63, sl = bid >> 6;
  int q0 = qb*QT;
  int tid = threadIdx.x;
  for (int idx=tid; idx<QT*DH/4; idx+=256)
    ((float4*)Mt)[idx] = ((const float4*)(MG + (size_t)q0*DH))[idx];
  if (tid < QT){ m_st[tid] = -1e30f; l_st[tid] = 0.f; }
  int qg = tid >> 5, kg = tid & 31;
  float o[4][8];
  #pragma unroll
  for (int a=0;a<4;a++){
    #pragma unroll
    for (int b2=0;b2<8;b2++) o[a][b2]=0.f;
  }
  int k0base = sl*SLICE;
  __syncthreads();
  for (int k0=0; k0<SLICE; k0+=KT){
    int kt = (SLICE-k0) < KT ? (SLICE-k0) : KT;
    for (int idx=tid; idx<KT*(DH/4); idx+=256){
      int r = idx/(DH/4), c = idx%(DH/4);
      if (r < kt)
        *(float4*)&Kt[r*KSTR + c*4] = ((const float4*)(G + (size_t)(k0base+k0+r)*DH))[c];
    }
    __syncthreads();
    float s[4][2];
    #pragma unroll
    for (int a=0;a<4;a++){ s[a][0]=0.f; s[a][1]=0.f; }
    #pragma unroll 4
    for (int d4=0; d4<DH/4; d4++){
      float4 k0v = *(float4*)&Kt[(kg*2+0)*KSTR + d4*4];
      float4 k1v = *(float4*)&Kt[(kg*2+1)*KSTR + d4*4];
      #pragma unroll
      for (int qi=0;qi<4;qi++){
        float4 mv = *(float4*)&Mt[(qg*4+qi)*DH + d4*4];
        s[qi][0] += mv.x*k0v.x + mv.y*k0v.y + mv.z*k0v.z + mv.w*k0v.w;
        s[qi][1] += mv.x*k1v.x + mv.y*k1v.y + mv.z*k1v.z + mv.w*k1v.w;
      }
    }
    bool v0 = (kg*2+0) < kt, v1 = (kg*2+1) < kt;
    #pragma unroll
    for (int qi=0;qi<4;qi++){
      if (!v0) s[qi][0] = -1e30f;
      if (!v1) s[qi][1] = -1e30f;
      int q = qg*4+qi;
      float mloc = fmaxf(s[qi][0], s[qi][1]);
      #pragma unroll
      for (int msk=16; msk>0; msk>>=1) mloc = fmaxf(mloc, __shfl_xor(mloc, msk, 64));
      float mold = m_st[q];
      float mnew = fmaxf(mold, mloc);
      float p0 = v0 ? __expf(s[qi][0]-mnew) : 0.f;
      float p1 = v1 ? __expf(s[qi][1]-mnew) : 0.f;
      float lloc = p0+p1;
      #pragma unroll
      for (int msk=16; msk>0; msk>>=1) lloc += __shfl_xor(lloc, msk, 64);
      float al = __expf(mold - mnew);
      if (kg==0){ m_st[q]=mnew; l_st[q] = l_st[q]*al + lloc; al_sh[q]=al; }
      Pt[q*(KT+2) + kg*2+0] = p0;
      Pt[q*(KT+2) + kg*2+1] = p1;
    }
    __syncthreads();
    int dg = kg;
    #pragma unroll
    for (int qi=0;qi<4;qi++){
      float al = al_sh[qg*4+qi];
      #pragma unroll
      for (int j=0;j<8;j++) o[qi][j] *= al;
    }
    for (int k=0;k<kt;k++){
      float4 vv0 = *(float4*)&Kt[k*KSTR + dg*8];
      float4 vv1 = *(float4*)&Kt[k*KSTR + dg*8+4];
      #pragma unroll
      for (int qi=0;qi<4;qi++){
        float p = Pt[(qg*4+qi)*(KT+2) + k];
        o[qi][0] = fmaf(p, vv0.x, o[qi][0]);
        o[qi][1] = fmaf(p, vv0.y, o[qi][1]);
        o[qi][2] = fmaf(p, vv0.z, o[qi][2]);
        o[qi][3] = fmaf(p, vv0.w, o[qi][3]);
        o[qi][4] = fmaf(p, vv1.x, o[qi][4]);
        o[qi][5] = fmaf(p, vv1.y, o[qi][5]);
        o[qi][6] = fmaf(p, vv1.z, o[qi][6]);
        o[qi][7] = fmaf(p, vv1.w, o[qi][7]);
      }
    }
    __syncthreads();
  }
  #pragma unroll
  for (int qi=0;qi<4;qi++){
    int q = q0 + qg*4 + qi;
    size_t base = ((size_t)sl*TT + q)*DH + kg*8;
    float4 w0 = make_float4(o[qi][0],o[qi][1],o[qi][2],o[qi][3]);
    float4 w1 = make_float4(o[qi][4],o[qi][5],o[qi][6],o[qi][7]);
    *(float4*)&OP[base]   = w0;
    *(float4*)&OP[base+4] = w1;
  }
  if (tid < QT){ MP[(size_t)sl*TT + q0 + tid] = m_st[tid]; LP[(size_t)sl*TT + q0 + tid] = l_st[tid]; }
}

// ---------------- combine flash splits ----------------
__global__ void k_combine(const float* __restrict__ OP, const float* __restrict__ MP,
                          const float* __restrict__ LP, float* __restrict__ CG){
  int q = blockIdx.x, tid = threadIdx.x; // 64 threads
  float m0 = MP[q], m1 = MP[TT+q], m2 = MP[2*TT+q], m3 = MP[3*TT+q];
  float M = fmaxf(fmaxf(m0,m1), fmaxf(m2,m3));
  float w0 = __expf(m0-M), w1 = __expf(m1-M), w2 = __expf(m2-M), w3 = __expf(m3-M);
  float denom = LP[q]*w0 + LP[TT+q]*w1 + LP[2*TT+q]*w2 + LP[3*TT+q]*w3;
  float inv = 1.f/denom;
  for (int d = tid; d < DH; d += 64){
    float v = OP[((size_t)0*TT+q)*DH+d]*w0 + OP[((size_t)1*TT+q)*DH+d]*w1
            + OP[((size_t)2*TT+q)*DH+d]*w2 + OP[((size_t)3*TT+q)*DH+d]*w3;
    CG[(size_t)q*DH + d] = v*inv;
  }
}

// ---------------- P_vocab softmax, mixture, final projection ----------------
__global__ void k_final(const float* __restrict__ out, const float* __restrict__ C,
        const float* __restrict__ CG, const float* __restrict__ BETA, const float* __restrict__ PGEN,
        const float* __restrict__ Wv_w, const float* __restrict__ Wv_b,
        const float* __restrict__ fc_w, const float* __restrict__ fc_b, float* __restrict__ O){
  int t = blockIdx.x, tid = threadIdx.x;
  __shared__ float cat[1024];
  __shared__ float pw[NLOC];
  __shared__ float mx; __shared__ float inv;
  cat[tid]     = out[(size_t)t*HH + tid];
  cat[tid+256] = out[(size_t)t*HH + tid+256];
  cat[512+tid] = C[(size_t)t*DH + tid];
  cat[768+tid] = CG[(size_t)t*DH + tid];
  __syncthreads();
  if (tid < NLOC){
    const float4* w = (const float4*)(Wv_w + (size_t)tid*1024);
    float acc = Wv_b[tid];
    for (int i4=0;i4<256;i4++){
      float4 wv = w[i4];
      acc += wv.x*cat[i4*4] + wv.y*cat[i4*4+1] + wv.z*cat[i4*4+2] + wv.w*cat[i4*4+3];
    }
    pw[tid] = acc;
  }
  __syncthreads();
  if (tid==0){ float m=pw[0]; for (int j=1;j<NLOC;j++) m=fmaxf(m,pw[j]); mx=m; }
  __syncthreads();
  if (tid<NLOC) pw[tid] = __expf(pw[tid]-mx);
  __syncthreads();
  if (tid==0){ float s=0.f; for(int j=0;j<NLOC;j++) s+=pw[j]; inv=1.f/s; }
  __syncthreads();
  float pg = PGEN[t];
  if (tid<NLOC) pw[tid] = pg*pw[tid]*inv + (1.f-pg)*BETA[(size_t)t*NLOC+tid];
  __syncthreads();
  for (int o_=tid; o_<VOCAB; o_+=256){
    const float4* fw = (const float4*)(fc_w + (size_t)o_*NLOC);
    float acc = fc_b[o_];
    #pragma unroll
    for (int p4=0;p4<25;p4++){
      float4 wv = fw[p4];
      acc += wv.x*pw[p4*4] + wv.y*pw[p4*4+1] + wv.z*pw[p4*4+2] + wv.w*pw[p4*4+3];
    }
    O[(size_t)t*VOCAB + o_] = acc;
  }
}

extern "C" void kernel_launch(void* const* d_in, const int* in_sizes, int n_in,
                              void* d_out, int out_size, void* d_ws, size_t ws_size,
                              hipStream_t stream) {
  (void)in_sizes; (void)n_in; (void)out_size; (void)ws_size;
  const int*   X    = (const int*)d_in[0];
  const float* glo  = (const float*)d_in[1];
  const float* loch = (const float*)d_in[2];
  const float* loco = (const float*)d_in[3];
  const float* emb  = (const float*)d_in[4];
  const float* W_ih = (const float*)d_in[5];
  const float* W_hh = (const float*)d_in[6];
  const float* b_ih = (const float*)d_in[7];
  const float* b_hh = (const float*)d_in[8];
  const float* Wg   = (const float*)d_in[9];
  const float* Wl   = (const float*)d_in[10];
  const float* Wv_w = (const float*)d_in[11];
  const float* Wv_b = (const float*)d_in[12];
  const float* wh   = (const float*)d_in[13];
  const float* wc   = (const float*)d_in[14];
  const float* wy   = (const float*)d_in[15];
  const float* fc_w = (const float*)d_in[16];
  const float* fc_b = (const float*)d_in[17];

  float* ws   = (float*)d_ws;
  float* Y    = ws + OFF_Y;
  float* GX   = ws + OFF_GX;
  float* OUT  = ws + OFF_OUT;
  unsigned long long* HBUF = (unsigned long long*)(ws + OFF_HBUF);
  float* MG   = ws + OFF_MG;
  float* ML   = ws + OFF_ML;
  float* C    = ws + OFF_C;
  float* CG   = ws + OFF_CG;
  float* BETA = ws + OFF_BETA;
  float* PGEN = ws + OFF_PGEN;
  float* OP   = ws + OFF_OP;
  float* MP   = ws + OFF_MP;
  float* LP   = ws + OFF_LP;

  hipMemsetAsync(HBUF, 0, 2*HH*sizeof(unsigned long long), stream);
  k_embed_gx<<<TT, 256, 0, stream>>>(X, emb, W_ih, b_ih, Y, GX);
  k_gru<<<GB, 256, 0, stream>>>(GX, W_hh, b_hh, glo, loch, OUT, HBUF);
  k_proj<<<TT, 256, 0, stream>>>(OUT, Y, Wg, Wl, wh, wy, MG, ML, PGEN);
  k_local<<<TT, 128, 0, stream>>>(ML, loco, wc, PGEN, C, BETA, PGEN);
  k_flash<<<QT*NSPL*2, 256, 0, stream>>>(MG, glo, OP, MP, LP);
  k_combine<<<TT, 64, 0, stream>>>(OP, MP, LP, CG);
  k_final<<<TT, 256, 0, stream>>>(OUT, C, CG, BETA, PGEN, Wv_w, Wv_b, fc_w, fc_b, (float*)d_out);
}

// Round 4
// 12747.867 us; speedup vs baseline: 1.3583x; 1.3583x over previous
//
#include <hip/hip_runtime.h>
#include <math.h>

#define TT 2048
#define NKEYS 50000
#define EE 128
#define HH 512
#define H3 1536
#define DH 256
#define VOCAB 1704
#define NLOC 100

#define GB 32      // GRU worker blocks
#define GC 16      // h-elements per GRU worker
#define GRID_GRU 256

#define QT 32      // flash queries per block
#define KT 64      // flash key tile
#define NSPL 4     // flash N-splits
#define SLICE 12500
#define KSTR 260   // padded LDS stride (f32) for K tile

// ---- workspace layout (float offsets) ----
static constexpr size_t OFF_Y     = 0;
static constexpr size_t OFF_GX    = OFF_Y    + (size_t)TT*EE;
static constexpr size_t OFF_OUT   = OFF_GX   + (size_t)TT*H3;
static constexpr size_t OFF_HBUF  = OFF_OUT  + (size_t)TT*HH;        // 2*HH uint64 = 4*HH floats
static constexpr size_t OFF_CLAIM = OFF_HBUF + 4*HH;                 // 2 ints (pad 8 floats)
static constexpr size_t OFF_MG    = OFF_CLAIM + 8;
static constexpr size_t OFF_ML    = OFF_MG   + (size_t)TT*DH;
static constexpr size_t OFF_C     = OFF_ML   + (size_t)TT*DH;
static constexpr size_t OFF_CG    = OFF_C    + (size_t)TT*DH;
static constexpr size_t OFF_BETA  = OFF_CG   + (size_t)TT*DH;
static constexpr size_t OFF_PGEN  = OFF_BETA + (size_t)TT*NLOC;
static constexpr size_t OFF_OP    = OFF_PGEN + TT;
static constexpr size_t OFF_MP    = OFF_OP   + (size_t)NSPL*TT*DH;
static constexpr size_t OFF_LP    = OFF_MP   + (size_t)NSPL*TT;

// ---------------- embedding + gx = y@W_ih^T + b_ih ----------------
__global__ void k_embed_gx(const int* __restrict__ X, const float* __restrict__ emb,
                           const float* __restrict__ W_ih, const float* __restrict__ b_ih,
                           float* __restrict__ Y, float* __restrict__ GX){
  int t = blockIdx.x, tid = threadIdx.x;
  __shared__ float yr[EE];
  int xid = X[t];
  if (tid < EE){ float v = emb[(size_t)xid*EE + tid]; yr[tid] = v; Y[(size_t)t*EE + tid] = v; }
  __syncthreads();
  for (int i=0;i<6;i++){
    int r = tid + 256*i;
    const float4* w = (const float4*)(W_ih + (size_t)r*EE);
    float acc = b_ih[r];
    #pragma unroll
    for (int k4=0;k4<EE/4;k4++){
      float4 wv = w[k4];
      acc += wv.x*yr[k4*4] + wv.y*yr[k4*4+1] + wv.z*yr[k4*4+2] + wv.w*yr[k4*4+3];
    }
    GX[(size_t)t*H3 + r] = acc;
  }
}

// ---------------- GRU scan: 32 workers claimed on ONE XCD, L2-local exchange ----------------
// Blocks read HW_REG_XCC_ID; blocks on XCD0 claim the 32 worker slots, others
// exit. Fallback (deadlock-proof): once all blocks have arrived, any block may
// claim a remaining slot — correctness never depends on the XCD mapping, only
// latency does. Exchange is R2-style: packed (seq<<32|h) u64, relaxed agent
// atomics, parity double-buffer, 2 polled words per thread.
__global__ __launch_bounds__(256) void k_gru(const float* __restrict__ GX, const float* __restrict__ W_hh,
          const float* __restrict__ b_hh, const float* __restrict__ glo, const float* __restrict__ loch,
          float* __restrict__ out, unsigned long long* hbuf, int* claim, int nblocks){
  __shared__ float wl[48*512];
  __shared__ float hl[512];
  __shared__ float gh[48];
  __shared__ int widx_sh;
  int tid = threadIdx.x;

  if (tid==0){
    unsigned xcc;
    asm volatile("s_getreg_b32 %0, hwreg(HW_REG_XCC_ID, 0, 32)" : "=s"(xcc));
    int my = -1;
    if (xcc == 0u) my = atomicAdd(&claim[0], 1);
    __hip_atomic_fetch_add(&claim[1], 1, __ATOMIC_RELAXED, __HIP_MEMORY_SCOPE_AGENT);
    if (my < 0){
      for(;;){
        int c = __hip_atomic_load(&claim[0], __ATOMIC_RELAXED, __HIP_MEMORY_SCOPE_AGENT);
        if (c >= GB) break;
        int a = __hip_atomic_load(&claim[1], __ATOMIC_RELAXED, __HIP_MEMORY_SCOPE_AGENT);
        if (a >= nblocks){ my = atomicAdd(&claim[0], 1); break; }
      }
    }
    widx_sh = my;
  }
  __syncthreads();
  int b = widx_sh;
  if (b < 0 || b >= GB) return;

  int i0 = b*GC;
  for (int idx = tid; idx < 48*128; idx += 256){
    int r = idx >> 7, c4 = idx & 127;
    int grow = (r<16) ? (i0 + r) : (r<32) ? (512 + i0 + (r-16)) : (1024 + i0 + (r-32));
    ((float4*)wl)[idx] = ((const float4*)W_hh)[(size_t)grow*128 + c4];
  }
  hl[tid]     = glo[tid];
  hl[tid+256] = loch[tid];
  float bhr=0.f,bhz=0.f,bhn=0.f;
  if (tid < GC){ bhr = b_hh[i0+tid]; bhz = b_hh[512+i0+tid]; bhn = b_hh[1024+i0+tid]; }
  __syncthreads();
  int wave = tid>>6, lane = tid&63;
  for (int t=0;t<TT;t++){
    // snapshot values needed after the barrier; issue gx loads early
    float gxr=0.f,gxz=0.f,gxn=0.f,hprev=0.f;
    if (tid < GC){
      size_t gbse = (size_t)t*H3;
      hprev = hl[i0+tid];
      gxr = GX[gbse + i0+tid]; gxz = GX[gbse + 512 + i0+tid]; gxn = GX[gbse + 1024 + i0+tid];
    }
    float hreg[8];
    #pragma unroll
    for (int m=0;m<8;m++) hreg[m] = hl[lane + 64*m];
    #pragma unroll
    for (int rr=0; rr<12; rr++){
      int row = wave*12 + rr;
      const float* wr = &wl[row*512];
      float s = 0.f;
      #pragma unroll
      for (int m=0;m<8;m++) s = fmaf(wr[lane+64*m], hreg[m], s);
      #pragma unroll
      for (int off=32; off>0; off>>=1) s += __shfl_xor(s, off, 64);
      if (lane==0) gh[row] = s;
    }
    __syncthreads();   // gh ready; all hl reads of step t complete
    int slot = (t+1)&1;
    if (tid < GC){
      int i = tid;
      float rg = 1.f/(1.f + __expf(-(gxr + gh[i]    + bhr)));
      float zg = 1.f/(1.f + __expf(-(gxz + gh[16+i] + bhz)));
      float nx = gxn + bhn + rg*gh[32+i];
      float ex = __expf(-2.f*fabsf(nx));
      float tt = (1.f-ex)/(1.f+ex);
      float ng = (nx >= 0.f) ? tt : -tt;
      float hn = (1.f - zg)*ng + zg*hprev;
      out[(size_t)t*HH + i0 + i] = hn;
      unsigned long long pk = ((unsigned long long)(unsigned)(t+1) << 32) | (unsigned long long)__float_as_uint(hn);
      __hip_atomic_store(&hbuf[slot*HH + i0 + i], pk, __ATOMIC_RELAXED, __HIP_MEMORY_SCOPE_AGENT);
    }
    if (t+1 < TT){
      unsigned int want = (unsigned)(t+1);
      unsigned long long v0=0ull, v1=0ull;
      bool r0=false, r1=false;
      do {
        if (!r0){ v0 = __hip_atomic_load(&hbuf[slot*HH + tid],     __ATOMIC_RELAXED, __HIP_MEMORY_SCOPE_AGENT); r0 = ((unsigned)(v0>>32) == want); }
        if (!r1){ v1 = __hip_atomic_load(&hbuf[slot*HH + tid+256], __ATOMIC_RELAXED, __HIP_MEMORY_SCOPE_AGENT); r1 = ((unsigned)(v1>>32) == want); }
      } while (!(r0 && r1));
      hl[tid]     = __uint_as_float((unsigned)v0);
      hl[tid+256] = __uint_as_float((unsigned)v1);
      __syncthreads();  // hl of step t+1 ready
    }
  }
}

// ---------------- M_g = out@W_ga_g, M_l = out@W_ga_l, pgen base ----------------
__global__ void k_proj(const float* __restrict__ out, const float* __restrict__ Y,
                       const float* __restrict__ Wg, const float* __restrict__ Wl,
                       const float* __restrict__ wh, const float* __restrict__ wy,
                       float* __restrict__ MG, float* __restrict__ ML, float* __restrict__ PGB){
  int t = blockIdx.x, tid = threadIdx.x;
  __shared__ float orow[512];
  __shared__ float red[256];
  orow[tid]     = out[(size_t)t*HH + tid];
  orow[tid+256] = out[(size_t)t*HH + tid+256];
  __syncthreads();
  float mg=0.f, ml=0.f;
  for (int h=0; h<HH; h++){
    float ov = orow[h];
    mg = fmaf(ov, Wg[(size_t)h*DH + tid], mg);
    ml = fmaf(ov, Wl[(size_t)h*DH + tid], ml);
  }
  MG[(size_t)t*DH + tid] = mg;
  ML[(size_t)t*DH + tid] = ml;
  float pr = orow[tid]*wh[tid] + orow[tid+256]*wh[tid+256];
  if (tid < EE) pr += Y[(size_t)t*EE + tid]*wy[tid];
  red[tid] = pr;
  __syncthreads();
  for (int s=128; s>0; s>>=1){ if (tid < s) red[tid] += red[tid+s]; __syncthreads(); }
  if (tid==0) PGB[t] = red[0];
}

// ---------------- local attention + p_gen ----------------
__global__ void k_local(const float* __restrict__ ML, const float* __restrict__ locout,
                        const float* __restrict__ wc, const float* __restrict__ PGB,
                        float* __restrict__ C, float* __restrict__ BETA, float* __restrict__ PGEN){
  int t = blockIdx.x, tid = threadIdx.x; // 128 threads
  __shared__ float mlr[DH];
  __shared__ float sl[NLOC];
  __shared__ float crow[DH];
  __shared__ float red[128];
  __shared__ float mx; __shared__ float inv;
  mlr[tid]     = ML[(size_t)t*DH + tid];
  mlr[tid+128] = ML[(size_t)t*DH + tid+128];
  __syncthreads();
  if (tid < NLOC){
    const float* gl = locout + (size_t)tid*8*DH;
    float s=0.f;
    for (int e=0;e<DH;e++) s = fmaf(gl[e], mlr[e], s);
    sl[tid] = s;
  }
  __syncthreads();
  if (tid==0){ float m = sl[0]; for (int j=1;j<NLOC;j++) m = fmaxf(m, sl[j]); mx = m; }
  __syncthreads();
  if (tid < NLOC) sl[tid] = __expf(sl[tid]-mx);
  __syncthreads();
  if (tid==0){ float su=0.f; for (int j=0;j<NLOC;j++) su += sl[j]; inv = 1.f/su; }
  __syncthreads();
  if (tid < NLOC){ sl[tid] *= inv; BETA[(size_t)t*NLOC + tid] = sl[tid]; }
  __syncthreads();
  {
    float c0=0.f, c1=0.f;
    for (int j=0;j<NLOC;j++){
      float ga = sl[j];
      c0 = fmaf(ga, locout[(size_t)j*8*DH + tid],     c0);
      c1 = fmaf(ga, locout[(size_t)j*8*DH + tid+128], c1);
    }
    C[(size_t)t*DH + tid]     = c0;
    C[(size_t)t*DH + tid+128] = c1;
    crow[tid] = c0; crow[tid+128] = c1;
  }
  __syncthreads();
  red[tid] = crow[tid]*wc[tid] + crow[tid+128]*wc[tid+128];
  __syncthreads();
  for (int s=64;s>0;s>>=1){ if (tid<s) red[tid]+=red[tid+s]; __syncthreads(); }
  if (tid==0){
    float x = PGB[t] + red[0];
    PGEN[t] = (x > 0.f) ? x : 0.2f*x;
  }
}

// ---------------- global flash attention (f32), 4-way N split ----------------
__global__ __launch_bounds__(256) void k_flash(const float* __restrict__ MG, const float* __restrict__ G,
        float* __restrict__ OP, float* __restrict__ MP, float* __restrict__ LP){
  __shared__ float Mt[QT*DH];
  __shared__ float Kt[KT*KSTR];
  __shared__ float Pt[QT*(KT+2)];
  __shared__ float m_st[QT]; __shared__ float l_st[QT]; __shared__ float al_sh[QT];
  int bid = blockIdx.x;
  int qb = bid & 63, sl = bid >> 6;
  int q0 = qb*QT;
  int tid = threadIdx.x;
  for (int idx=tid; idx<QT*DH/4; idx+=256)
    ((float4*)Mt)[idx] = ((const float4*)(MG + (size_t)q0*DH))[idx];
  if (tid < QT){ m_st[tid] = -1e30f; l_st[tid] = 0.f; }
  int qg = tid >> 5, kg = tid & 31;
  float o[4][8];
  #pragma unroll
  for (int a=0;a<4;a++){
    #pragma unroll
    for (int b2=0;b2<8;b2++) o[a][b2]=0.f;
  }
  int k0base = sl*SLICE;
  __syncthreads();
  for (int k0=0; k0<SLICE; k0+=KT){
    int kt = (SLICE-k0) < KT ? (SLICE-k0) : KT;
    for (int idx=tid; idx<KT*(DH/4); idx+=256){
      int r = idx/(DH/4), c = idx%(DH/4);
      if (r < kt)
        *(float4*)&Kt[r*KSTR + c*4] = ((const float4*)(G + (size_t)(k0base+k0+r)*DH))[c];
    }
    __syncthreads();
    float s[4][2];
    #pragma unroll
    for (int a=0;a<4;a++){ s[a][0]=0.f; s[a][1]=0.f; }
    #pragma unroll 4
    for (int d4=0; d4<DH/4; d4++){
      float4 k0v = *(float4*)&Kt[(kg*2+0)*KSTR + d4*4];
      float4 k1v = *(float4*)&Kt[(kg*2+1)*KSTR + d4*4];
      #pragma unroll
      for (int qi=0;qi<4;qi++){
        float4 mv = *(float4*)&Mt[(qg*4+qi)*DH + d4*4];
        s[qi][0] += mv.x*k0v.x + mv.y*k0v.y + mv.z*k0v.z + mv.w*k0v.w;
        s[qi][1] += mv.x*k1v.x + mv.y*k1v.y + mv.z*k1v.z + mv.w*k1v.w;
      }
    }
    bool v0 = (kg*2+0) < kt, v1 = (kg*2+1) < kt;
    #pragma unroll
    for (int qi=0;qi<4;qi++){
      if (!v0) s[qi][0] = -1e30f;
      if (!v1) s[qi][1] = -1e30f;
      int q = qg*4+qi;
      float mloc = fmaxf(s[qi][0], s[qi][1]);
      #pragma unroll
      for (int msk=16; msk>0; msk>>=1) mloc = fmaxf(mloc, __shfl_xor(mloc, msk, 64));
      float mold = m_st[q];
      float mnew = fmaxf(mold, mloc);
      float p0 = v0 ? __expf(s[qi][0]-mnew) : 0.f;
      float p1 = v1 ? __expf(s[qi][1]-mnew) : 0.f;
      float lloc = p0+p1;
      #pragma unroll
      for (int msk=16; msk>0; msk>>=1) lloc += __shfl_xor(lloc, msk, 64);
      float al = __expf(mold - mnew);
      if (kg==0){ m_st[q]=mnew; l_st[q] = l_st[q]*al + lloc; al_sh[q]=al; }
      Pt[q*(KT+2) + kg*2+0] = p0;
      Pt[q*(KT+2) + kg*2+1] = p1;
    }
    __syncthreads();
    int dg = kg;
    #pragma unroll
    for (int qi=0;qi<4;qi++){
      float al = al_sh[qg*4+qi];
      #pragma unroll
      for (int j=0;j<8;j++) o[qi][j] *= al;
    }
    for (int k=0;k<kt;k++){
      float4 vv0 = *(float4*)&Kt[k*KSTR + dg*8];
      float4 vv1 = *(float4*)&Kt[k*KSTR + dg*8+4];
      #pragma unroll
      for (int qi=0;qi<4;qi++){
        float p = Pt[(qg*4+qi)*(KT+2) + k];
        o[qi][0] = fmaf(p, vv0.x, o[qi][0]);
        o[qi][1] = fmaf(p, vv0.y, o[qi][1]);
        o[qi][2] = fmaf(p, vv0.z, o[qi][2]);
        o[qi][3] = fmaf(p, vv0.w, o[qi][3]);
        o[qi][4] = fmaf(p, vv1.x, o[qi][4]);
        o[qi][5] = fmaf(p, vv1.y, o[qi][5]);
        o[qi][6] = fmaf(p, vv1.z, o[qi][6]);
        o[qi][7] = fmaf(p, vv1.w, o[qi][7]);
      }
    }
    __syncthreads();
  }
  #pragma unroll
  for (int qi=0;qi<4;qi++){
    int q = q0 + qg*4 + qi;
    size_t base = ((size_t)sl*TT + q)*DH + kg*8;
    float4 w0 = make_float4(o[qi][0],o[qi][1],o[qi][2],o[qi][3]);
    float4 w1 = make_float4(o[qi][4],o[qi][5],o[qi][6],o[qi][7]);
    *(float4*)&OP[base]   = w0;
    *(float4*)&OP[base+4] = w1;
  }
  if (tid < QT){ MP[(size_t)sl*TT + q0 + tid] = m_st[tid]; LP[(size_t)sl*TT + q0 + tid] = l_st[tid]; }
}

// ---------------- combine flash splits ----------------
__global__ void k_combine(const float* __restrict__ OP, const float* __restrict__ MP,
                          const float* __restrict__ LP, float* __restrict__ CG){
  int q = blockIdx.x, tid = threadIdx.x; // 64 threads
  float m0 = MP[q], m1 = MP[TT+q], m2 = MP[2*TT+q], m3 = MP[3*TT+q];
  float M = fmaxf(fmaxf(m0,m1), fmaxf(m2,m3));
  float w0 = __expf(m0-M), w1 = __expf(m1-M), w2 = __expf(m2-M), w3 = __expf(m3-M);
  float denom = LP[q]*w0 + LP[TT+q]*w1 + LP[2*TT+q]*w2 + LP[3*TT+q]*w3;
  float inv = 1.f/denom;
  for (int d = tid; d < DH; d += 64){
    float v = OP[((size_t)0*TT+q)*DH+d]*w0 + OP[((size_t)1*TT+q)*DH+d]*w1
            + OP[((size_t)2*TT+q)*DH+d]*w2 + OP[((size_t)3*TT+q)*DH+d]*w3;
    CG[(size_t)q*DH + d] = v*inv;
  }
}

// ---------------- P_vocab softmax, mixture, final projection ----------------
__global__ void k_final(const float* __restrict__ out, const float* __restrict__ C,
        const float* __restrict__ CG, const float* __restrict__ BETA, const float* __restrict__ PGEN,
        const float* __restrict__ Wv_w, const float* __restrict__ Wv_b,
        const float* __restrict__ fc_w, const float* __restrict__ fc_b, float* __restrict__ O){
  int t = blockIdx.x, tid = threadIdx.x;
  __shared__ float cat[1024];
  __shared__ float pw[NLOC];
  __shared__ float mx; __shared__ float inv;
  cat[tid]     = out[(size_t)t*HH + tid];
  cat[tid+256] = out[(size_t)t*HH + tid+256];
  cat[512+tid] = C[(size_t)t*DH + tid];
  cat[768+tid] = CG[(size_t)t*DH + tid];
  __syncthreads();
  if (tid < NLOC){
    const float4* w = (const float4*)(Wv_w + (size_t)tid*1024);
    float acc = Wv_b[tid];
    for (int i4=0;i4<256;i4++){
      float4 wv = w[i4];
      acc += wv.x*cat[i4*4] + wv.y*cat[i4*4+1] + wv.z*cat[i4*4+2] + wv.w*cat[i4*4+3];
    }
    pw[tid] = acc;
  }
  __syncthreads();
  if (tid==0){ float m=pw[0]; for (int j=1;j<NLOC;j++) m=fmaxf(m,pw[j]); mx=m; }
  __syncthreads();
  if (tid<NLOC) pw[tid] = __expf(pw[tid]-mx);
  __syncthreads();
  if (tid==0){ float s=0.f; for(int j=0;j<NLOC;j++) s+=pw[j]; inv=1.f/s; }
  __syncthreads();
  float pg = PGEN[t];
  if (tid<NLOC) pw[tid] = pg*pw[tid]*inv + (1.f-pg)*BETA[(size_t)t*NLOC+tid];
  __syncthreads();
  for (int o_=tid; o_<VOCAB; o_+=256){
    const float4* fw = (const float4*)(fc_w + (size_t)o_*NLOC);
    float acc = fc_b[o_];
    #pragma unroll
    for (int p4=0;p4<25;p4++){
      float4 wv = fw[p4];
      acc += wv.x*pw[p4*4] + wv.y*pw[p4*4+1] + wv.z*pw[p4*4+2] + wv.w*pw[p4*4+3];
    }
    O[(size_t)t*VOCAB + o_] = acc;
  }
}

extern "C" void kernel_launch(void* const* d_in, const int* in_sizes, int n_in,
                              void* d_out, int out_size, void* d_ws, size_t ws_size,
                              hipStream_t stream) {
  (void)in_sizes; (void)n_in; (void)out_size; (void)ws_size;
  const int*   X    = (const int*)d_in[0];
  const float* glo  = (const float*)d_in[1];
  const float* loch = (const float*)d_in[2];
  const float* loco = (const float*)d_in[3];
  const float* emb  = (const float*)d_in[4];
  const float* W_ih = (const float*)d_in[5];
  const float* W_hh = (const float*)d_in[6];
  const float* b_ih = (const float*)d_in[7];
  const float* b_hh = (const float*)d_in[8];
  const float* Wg   = (const float*)d_in[9];
  const float* Wl   = (const float*)d_in[10];
  const float* Wv_w = (const float*)d_in[11];
  const float* Wv_b = (const float*)d_in[12];
  const float* wh   = (const float*)d_in[13];
  const float* wc   = (const float*)d_in[14];
  const float* wy   = (const float*)d_in[15];
  const float* fc_w = (const float*)d_in[16];
  const float* fc_b = (const float*)d_in[17];

  float* ws   = (float*)d_ws;
  float* Y    = ws + OFF_Y;
  float* GX   = ws + OFF_GX;
  float* OUT  = ws + OFF_OUT;
  unsigned long long* HBUF = (unsigned long long*)(ws + OFF_HBUF);
  int*   CLAIM = (int*)(ws + OFF_CLAIM);
  float* MG   = ws + OFF_MG;
  float* ML   = ws + OFF_ML;
  float* C    = ws + OFF_C;
  float* CG   = ws + OFF_CG;
  float* BETA = ws + OFF_BETA;
  float* PGEN = ws + OFF_PGEN;
  float* OP   = ws + OFF_OP;
  float* MP   = ws + OFF_MP;
  float* LP   = ws + OFF_LP;

  hipMemsetAsync(HBUF, 0, 2*HH*sizeof(unsigned long long), stream);
  hipMemsetAsync(CLAIM, 0, 2*sizeof(int), stream);
  k_embed_gx<<<TT, 256, 0, stream>>>(X, emb, W_ih, b_ih, Y, GX);
  k_gru<<<GRID_GRU, 256, 0, stream>>>(GX, W_hh, b_hh, glo, loch, OUT, HBUF, CLAIM, GRID_GRU);
  k_proj<<<TT, 256, 0, stream>>>(OUT, Y, Wg, Wl, wh, wy, MG, ML, PGEN);
  k_local<<<TT, 128, 0, stream>>>(ML, loco, wc, PGEN, C, BETA, PGEN);
  k_flash<<<QT*NSPL*2, 256, 0, stream>>>(MG, glo, OP, MP, LP);
  k_combine<<<TT, 64, 0, stream>>>(OP, MP, LP, CG);
  k_final<<<TT, 256, 0, stream>>>(OUT, C, CG, BETA, PGEN, Wv_w, Wv_b, fc_w, fc_b, (float*)d_out);
}